// Round 6
// baseline (235.279 us; speedup 1.0000x reference)
//
#include <hip/hip_runtime.h>
#include <hip/hip_cooperative_groups.h>
#include <math.h>

namespace cg = cooperative_groups;

// N = 2^22, 22 stages of real-butterfly + magnitude (|.| after every stage —
// stage order fixed, NOT commutable like a true FFT).
// Stage s (m=2^s) pairs (p, p+m/2), twiddle fraction r = (p mod m/2)/m revolutions:
//   out_e = sqrt((e + c*o)^2 + (s*o)^2), out_o = sqrt((e - c*o)^2 + (s*o)^2).
//
// SINGLE cooperative kernel, 512 blocks x 256 threads (2 blocks/CU co-resident),
// grid.sync() between phases (replaces 2 dispatch boundaries = launch + drain):
//   P: tiled bitrev permute (64x65 LDS tile, 2 tiles/block) + stages 1-3
//   A: stages 4-13 in contiguous 8192-chunk: radix-32, one LDS transpose, radix-32
//   B: stages 14-22 over 512-elem stride-8192 combs: radix-32, transpose, 2x radix-16
//
// All twiddles per radix group from ONE sincos via exact double-angle + constexpr
// rotation constants (immediates). v_sin/v_cos take REVOLUTIONS.

#define RSQ2 0.70710678118654752440f

__device__ __forceinline__ float hsqrt(float x) { return __builtin_amdgcn_sqrtf(x); }

__device__ __forceinline__ void bf(float& e, float& o, float c, float s) {
    float rp = fmaf(c, o, e);
    float rm = fmaf(-c, o, e);
    float im = s * o;
    float im2 = im * im;
    e = hsqrt(fmaf(rp, rp, im2));
    o = hsqrt(fmaf(rm, rm, im2));
}
__device__ __forceinline__ void bf0(float& e, float& o) {   // twiddle (1,0)
    float a = e + o, b = e - o;
    e = fabsf(a); o = fabsf(b);
}
__device__ __forceinline__ void bfq(float& e, float& o) {   // twiddle (0,1)
    float h = hsqrt(fmaf(e, e, o * o));
    e = h; o = h;
}

// Rotation constants cos/sin(pi*k/16) as constexpr -> folded to immediates.
constexpr float KCc[16] = {
    1.f, 0.980785280f, 0.923879533f, 0.831469612f, 0.707106781f, 0.555570233f,
    0.382683432f, 0.195090322f, 0.f, -0.195090322f, -0.382683432f, -0.555570233f,
    -0.707106781f, -0.831469612f, -0.923879533f, -0.980785280f };
constexpr float KSc[16] = {
    0.f, 0.195090322f, 0.382683432f, 0.555570233f, 0.707106781f, 0.831469612f,
    0.923879533f, 0.980785280f, 1.f, 0.980785280f, 0.923879533f, 0.831469612f,
    0.707106781f, 0.555570233f, 0.382683432f, 0.195090322f };

// radix-2^L (L<=5) on v[0..2^L), elements at p = P0 + j*H.
// (c,s) = cos/sin of r_base = P0 / (2^L * H) revolutions (LAST sub-stage base).
template <int L>
__device__ __forceinline__ void radixN(float* v, float c, float s) {
    float ca[L], sa[L];
    ca[L - 1] = c; sa[L - 1] = s;
#pragma unroll
    for (int a = L - 1; a > 0; --a) {
        ca[a - 1] = fmaf(-2.f * sa[a], sa[a], 1.f);
        sa[a - 1] = 2.f * sa[a] * ca[a];
    }
#pragma unroll
    for (int a = 0; a < L; ++a) {
        const int half = 1 << a;
#pragma unroll
        for (int d = 0; d < half; ++d) {
            const int k = d << (4 - a);
            float cd = fmaf(ca[a], KCc[k], -sa[a] * KSc[k]);
            float sd = fmaf(sa[a], KCc[k],  ca[a] * KSc[k]);
#pragma unroll
            for (int g = d; g < (1 << L); g += 2 * half)
                bf(v[g], v[g + half], cd, sd);
        }
    }
}

// stages 1..3 (twiddles all constant)
__device__ __forceinline__ void radix8z(float v[8]) {
    bf0(v[0], v[1]); bf0(v[2], v[3]); bf0(v[4], v[5]); bf0(v[6], v[7]);
    bf0(v[0], v[2]); bf0(v[4], v[6]);
    bfq(v[1], v[3]); bfq(v[5], v[7]);
    bf0(v[0], v[4]);
    bf(v[1], v[5], RSQ2, RSQ2);
    bfq(v[2], v[6]);
    bf(v[3], v[7], -RSQ2, RSQ2);
}

__global__ __launch_bounds__(256, 2) void fft_fused(const float* __restrict__ x,
                                                    float* __restrict__ y) {
    __shared__ float lds[8752];
    cg::grid_group grid = cg::this_grid();
    const unsigned tid = threadIdx.x;
    const unsigned bid = blockIdx.x;

    // ---------------- Phase P: bitrev permute + stages 1..3 ----------------
    // p = hi11*2048 + lo11; brev22(p) = brev11(lo11)*2048 + brev11(hi11).
    {
        const unsigned tx = tid & 63, g = tid >> 6;
#pragma unroll
        for (int q = 0; q < 2; ++q) {
            const unsigned tile = bid * 2u + q;
            const unsigned C0 = (tile & 31) * 64;
            const unsigned B0 = (tile >> 5) * 64;
#pragma unroll
            for (int k = 0; k < 16; ++k) {
                unsigned r = g * 16 + k;
                unsigned a = __brev(C0 + r) >> (32 - 11);
                lds[r * 65 + tx] = x[a * 2048u + B0 + tx];
            }
            __syncthreads();
            float v[8];
#pragma unroll
            for (int qq = 0; qq < 2; ++qq) {
                unsigned task = tid + 256u * qq;
                unsigned c = task >> 3, grp = task & 7;
#pragma unroll
                for (int j = 0; j < 8; ++j) v[j] = lds[(grp * 8 + j) * 65 + c];
                radix8z(v);
                unsigned pr = __brev(B0 + c) >> (32 - 11);
                float* dst = y + pr * 2048u + C0 + grp * 8;
                *(float4*)(dst)     = make_float4(v[0], v[1], v[2], v[3]);
                *(float4*)(dst + 4) = make_float4(v[4], v[5], v[6], v[7]);
            }
            __syncthreads();   // lds reused by next tile / next phase
        }
    }
    grid.sync();

    // ---------------- Phase A: stages 4..13 (chunk = bid) ----------------
    // LDS pad addr(q) = q + (q>>5): phase-1 writes & phase-2 reads both <=2-way.
    {
        const unsigned base = bid * 8192u;
        const unsigned lo = tid & 7, hi = tid >> 3;      // hi 0..31
        float v[32];

        // stages 4..8 on {lo + 8j + 256hi}, straight from global
        {
            const float* src = y + base + lo + 256u * hi;
#pragma unroll
            for (int j = 0; j < 32; ++j) v[j] = src[8 * j];
            float r = (float)lo * (1.f / 256.f);
            radixN<5>(v, __builtin_amdgcn_cosf(r), __builtin_amdgcn_sinf(r));
#pragma unroll
            for (int j = 0; j < 32; ++j) {
                unsigned q = lo + 8u * j + 256u * hi;
                lds[q + (q >> 5)] = v[j];
            }
        }
        __syncthreads();

        // stages 9..13 on {t + 256j}, store coalesced
        {
#pragma unroll
            for (int j = 0; j < 32; ++j) {
                unsigned q = tid + 256u * j;
                v[j] = lds[q + (q >> 5)];
            }
            float r = (float)tid * (1.f / 8192.f);
            radixN<5>(v, __builtin_amdgcn_cosf(r), __builtin_amdgcn_sinf(r));
            float* dst = y + base + tid;
#pragma unroll
            for (int j = 0; j < 32; ++j) dst[256u * j] = v[j];
        }
    }
    grid.sync();

    // ---------------- Phase B: stages 14..22 ----------------
    // 16 lows x 512 t (stride 8192). LDS addr(t,li) = t*17 + (t>>5) + li.
    {
        const unsigned li = tid & 15, u5 = tid >> 4;     // u5 0..15
        const unsigned low = bid * 16u + li;
        float v[32];

        // stages 14..18 on t = 32*u5 + j
        {
            const float* src = y + low;
#pragma unroll
            for (int j = 0; j < 32; ++j) v[j] = src[8192u * (32u * u5 + j)];
            float r = (float)low * (1.f / 262144.f);
            radixN<5>(v, __builtin_amdgcn_cosf(r), __builtin_amdgcn_sinf(r));
#pragma unroll
            for (int j = 0; j < 32; ++j) {
                unsigned trow = 32u * u5 + j;
                lds[trow * 17 + (trow >> 5) + li] = v[j];
            }
        }
        __syncthreads();

        // stages 19..22: two radix-16 groups t0 = 2*u5 + b, t = t0 + 32j
#pragma unroll
        for (int b = 0; b < 2; ++b) {
            const unsigned t0 = 2u * u5 + b;
            float* w = v + 16 * b;
#pragma unroll
            for (int j = 0; j < 16; ++j) {
                unsigned trow = t0 + 32u * j;
                w[j] = lds[trow * 17 + (trow >> 5) + li];
            }
            float r = ((float)low + 8192.f * (float)t0) * (1.f / 4194304.f);
            radixN<4>(w, __builtin_amdgcn_cosf(r), __builtin_amdgcn_sinf(r));
#pragma unroll
            for (int j = 0; j < 16; ++j)
                y[low + 8192u * (t0 + 32u * j)] = w[j];
        }
    }
}

extern "C" void kernel_launch(void* const* d_in, const int* in_sizes, int n_in,
                              void* d_out, int out_size, void* d_ws, size_t ws_size,
                              hipStream_t stream) {
    const float* x = (const float*)d_in[0];
    float* out = (float*)d_out;

    void* args[] = { (void*)&x, (void*)&out };
    hipLaunchCooperativeKernel((const void*)fft_fused, dim3(512), dim3(256),
                               args, 0, stream);
}

// Round 7
// 100.171 us; speedup vs baseline: 2.3488x; 2.3488x over previous
//
#include <hip/hip_runtime.h>
#include <math.h>

// N = 2^22, 22 stages of real-butterfly + magnitude (|.| after every stage —
// stage order fixed, NOT commutable like a true FFT).
// Stage s (m=2^s) pairs (p, p+m/2), twiddle fraction r = (p mod m/2)/m revolutions:
//   out_e = sqrt((e + c*o)^2 + (s*o)^2), out_o = sqrt((e - c*o)^2 + (s*o)^2).
//
// P: tiled bitrev permute (64x65 LDS tile) + stages 1-3 (constant twiddles).
// A: stages 4-13 in contiguous 8192-chunks: radix-32 (stages 4-8 straight from
//    global, stride-8 comb) -> ONE LDS transpose -> radix-32 (stages 9-13).
// B: stages 14-22 over 512-elem stride-8192 combs: radix-32 (14-18) -> ONE LDS
//    transpose -> 2x radix-16 (19-22).
//
// NOTE (R6 post-mortem): do NOT fuse these with cooperative grid.sync() — two
// grid syncs on 8 XCDs cost ~120 us vs ~5 us of dispatch gaps. Separate
// dispatches in the captured graph are the fast path.
//
// All twiddles in a radix group derive from ONE sincos via exact double-angle
// + constant rotations (cos/sin(pi*k/16) table). v_sin/v_cos take REVOLUTIONS.

#define NBITS 22
#define RSQ2 0.70710678118654752440f

__device__ __forceinline__ float hsqrt(float x) { return __builtin_amdgcn_sqrtf(x); }

__device__ __forceinline__ void bf(float& e, float& o, float c, float s) {
    float rp = fmaf(c, o, e);
    float rm = fmaf(-c, o, e);
    float im = s * o;
    float im2 = im * im;
    e = hsqrt(fmaf(rp, rp, im2));
    o = hsqrt(fmaf(rm, rm, im2));
}
__device__ __forceinline__ void bf0(float& e, float& o) {   // twiddle (1,0)
    float a = e + o, b = e - o;
    e = fabsf(a); o = fabsf(b);
}
__device__ __forceinline__ void bfq(float& e, float& o) {   // twiddle (0,1)
    float h = hsqrt(fmaf(e, e, o * o));
    e = h; o = h;
}

// Rotation constants: KC[k]=cos(pi*k/16), KS[k]=sin(pi*k/16) (offset k/32 rev).
__device__ __constant__ float KC[16] = {
    1.f, 0.980785280f, 0.923879533f, 0.831469612f, 0.707106781f, 0.555570233f,
    0.382683432f, 0.195090322f, 0.f, -0.195090322f, -0.382683432f, -0.555570233f,
    -0.707106781f, -0.831469612f, -0.923879533f, -0.980785280f };
__device__ __constant__ float KS[16] = {
    0.f, 0.195090322f, 0.382683432f, 0.555570233f, 0.707106781f, 0.831469612f,
    0.923879533f, 0.980785280f, 1.f, 0.980785280f, 0.923879533f, 0.831469612f,
    0.707106781f, 0.555570233f, 0.382683432f, 0.195090322f };

// radix-2^L (L<=5) on v[0..2^L), elements at p = P0 + j*H.
// (c,s) = cos/sin of r_base = P0 / (2^L * H) revolutions (LAST sub-stage base).
template <int L>
__device__ __forceinline__ void radixN(float* v, float c, float s) {
    float ca[L], sa[L];
    ca[L - 1] = c; sa[L - 1] = s;
#pragma unroll
    for (int a = L - 1; a > 0; --a) {
        ca[a - 1] = fmaf(-2.f * sa[a], sa[a], 1.f);
        sa[a - 1] = 2.f * sa[a] * ca[a];
    }
#pragma unroll
    for (int a = 0; a < L; ++a) {
        const int half = 1 << a;
#pragma unroll
        for (int d = 0; d < half; ++d) {
            const int k = d << (4 - a);
            float cd = fmaf(ca[a], KC[k], -sa[a] * KS[k]);
            float sd = fmaf(sa[a], KC[k],  ca[a] * KS[k]);
#pragma unroll
            for (int g = d; g < (1 << L); g += 2 * half)
                bf(v[g], v[g + half], cd, sd);
        }
    }
}

// stages 1..3 (twiddles all constant)
__device__ __forceinline__ void radix8z(float v[8]) {
    bf0(v[0], v[1]); bf0(v[2], v[3]); bf0(v[4], v[5]); bf0(v[6], v[7]);
    bf0(v[0], v[2]); bf0(v[4], v[6]);
    bfq(v[1], v[3]); bfq(v[5], v[7]);
    bf0(v[0], v[4]);
    bf(v[1], v[5], RSQ2, RSQ2);
    bfq(v[2], v[6]);
    bf(v[3], v[7], -RSQ2, RSQ2);
}

// ---------------- Kernel P: bitrev permute + stages 1..3 ----------------
// p = hi11*2048 + lo11; brev22(p) = brev11(lo11)*2048 + brev11(hi11).
__global__ __launch_bounds__(256, 8) void fft_perm(const float* __restrict__ x,
                                                   float* __restrict__ y) {
    __shared__ float lds[64 * 65];
    const unsigned tid = threadIdx.x;
    const unsigned tx = tid & 63, g = tid >> 6;
    const unsigned C0 = (blockIdx.x & 31) * 64;
    const unsigned B0 = (blockIdx.x >> 5) * 64;

#pragma unroll
    for (int k = 0; k < 16; ++k) {
        unsigned r = g * 16 + k;
        unsigned a = __brev(C0 + r) >> (32 - 11);
        lds[r * 65 + tx] = x[a * 2048u + B0 + tx];
    }
    __syncthreads();

    float v[8];
#pragma unroll
    for (int q = 0; q < 2; ++q) {
        unsigned task = tid + 256u * q;
        unsigned c = task >> 3, grp = task & 7;
#pragma unroll
        for (int j = 0; j < 8; ++j) v[j] = lds[(grp * 8 + j) * 65 + c];
        radix8z(v);
        unsigned pr = __brev(B0 + c) >> (32 - 11);
        float* dst = y + pr * 2048u + C0 + grp * 8;
        *(float4*)(dst)     = make_float4(v[0], v[1], v[2], v[3]);
        *(float4*)(dst + 4) = make_float4(v[4], v[5], v[6], v[7]);
    }
}

// ---------------- Kernel A: stages 4..13 ----------------
// LDS pad: addr(q) = q + (q>>5). Phase-1 writes (q = lo+8j+256hi, lanes vary
// lo,hi) and phase-2 reads (q = t+256j, lanes vary t) are both <=2-way.
__global__ __launch_bounds__(256, 4) void fft_low(float* __restrict__ y) {
    __shared__ float lds[8448];                   // 8191 + 255 + 1, padded
    const unsigned t = threadIdx.x;               // 0..255
    const unsigned base = blockIdx.x * 8192;
    const unsigned lo = t & 7, hi = t >> 3;       // hi 0..31
    float v[32];

    // phase 1: stages 4..8 on {lo + 8j + 256hi}, straight from global
    {
        const float* src = y + base + lo + 256u * hi;
#pragma unroll
        for (int j = 0; j < 32; ++j) v[j] = src[8 * j];
        float r = (float)lo * (1.f / 256.f);      // r_base = P0/(32*8)
        radixN<5>(v, __builtin_amdgcn_cosf(r), __builtin_amdgcn_sinf(r));
#pragma unroll
        for (int j = 0; j < 32; ++j) {
            unsigned q = lo + 8u * j + 256u * hi;
            lds[q + (q >> 5)] = v[j];
        }
    }
    __syncthreads();

    // phase 2: stages 9..13 on {t + 256j}, store coalesced
    {
#pragma unroll
        for (int j = 0; j < 32; ++j) {
            unsigned q = t + 256u * j;
            v[j] = lds[q + (q >> 5)];
        }
        float r = (float)t * (1.f / 8192.f);      // r_base = P0/(32*256)
        radixN<5>(v, __builtin_amdgcn_cosf(r), __builtin_amdgcn_sinf(r));
        float* dst = y + base + t;
#pragma unroll
        for (int j = 0; j < 32; ++j) dst[256u * j] = v[j];
    }
}

// ---------------- Kernel B: stages 14..22 ----------------
// 16 lows x 512 t (stride 8192). LDS addr(t,li) = t*17 + (t>>5) + li:
// phase-1 writes (t=32u5+j) and phase-2 reads (t=t0+32j) both <=2-way.
__global__ __launch_bounds__(256, 4) void fft_high(float* __restrict__ y) {
    __shared__ float lds[512 * 17 + 32];
    const unsigned tt = threadIdx.x;
    const unsigned li = tt & 15, u5 = tt >> 4;    // u5 0..15
    const unsigned low = blockIdx.x * 16 + li;
    float v[32];

    // phase 1: stages 14..18 on t = 32*u5 + j
    {
        const float* src = y + low;
#pragma unroll
        for (int j = 0; j < 32; ++j) v[j] = src[8192u * (32u * u5 + j)];
        float r = (float)low * (1.f / 262144.f);  // r_base = low/(32*8192)
        radixN<5>(v, __builtin_amdgcn_cosf(r), __builtin_amdgcn_sinf(r));
#pragma unroll
        for (int j = 0; j < 32; ++j) {
            unsigned trow = 32u * u5 + j;
            lds[trow * 17 + (trow >> 5) + li] = v[j];
        }
    }
    __syncthreads();

    // phase 2: stages 19..22, two radix-16 groups t0 = 2*u5 + b, t = t0 + 32j
#pragma unroll
    for (int b = 0; b < 2; ++b) {
        const unsigned t0 = 2u * u5 + b;
        float* w = v + 16 * b;
#pragma unroll
        for (int j = 0; j < 16; ++j) {
            unsigned trow = t0 + 32u * j;
            w[j] = lds[trow * 17 + (trow >> 5) + li];
        }
        float r = ((float)low + 8192.f * (float)t0) * (1.f / 4194304.f);
        radixN<4>(w, __builtin_amdgcn_cosf(r), __builtin_amdgcn_sinf(r));
#pragma unroll
        for (int j = 0; j < 16; ++j)
            y[low + 8192u * (t0 + 32u * j)] = w[j];
    }
}

extern "C" void kernel_launch(void* const* d_in, const int* in_sizes, int n_in,
                              void* d_out, int out_size, void* d_ws, size_t ws_size,
                              hipStream_t stream) {
    const float* x = (const float*)d_in[0];
    float* out = (float*)d_out;

    fft_perm<<<dim3(1024), dim3(256), 0, stream>>>(x, out);
    fft_low<<<dim3(512), dim3(256), 0, stream>>>(out);
    fft_high<<<dim3(512), dim3(256), 0, stream>>>(out);
}